// Round 3
// baseline (9003.656 us; speedup 1.0000x reference)
//
#include <hip/hip_runtime.h>
#include <stdint.h>

typedef unsigned short u16;
typedef unsigned long long u64;
typedef __attribute__((ext_vector_type(8))) short short8;
typedef __attribute__((ext_vector_type(4))) float f32x4;

#define B_ 32
#define S_ 512
#define H_ 1024
#define NBLK 64   // recurrence workgroups (<=256 CUs -> co-resident, spin barrier safe)

// ---- workspace layout (bytes), total ~144.2 MiB (UNCHANGED from round 2 -> known to fit) ----
static const size_t OFF_BAR  = 0;                         // barrier counter + dtype flag
static const size_t OFF_HBF  = 256;                       // h double buffer: 2*32*1024*2
static const size_t OFF_BIAS = OFF_HBF + 131072 + 256;    // fp32[4096]
static const size_t OFF_UT   = OFF_BIAS + 16384;          // U^T bf16 [4096][1024]
static const size_t OFF_VP   = OFF_UT + 8388608;          // V fragment-permuted bf16
static const size_t OFF_XU   = OFF_VP + 8388608;          // xu bf16 [512][32][4096]
static const size_t WS_NEED  = OFF_XU + (size_t)S_ * B_ * 4 * H_ * 2;

__device__ inline float bf2f(u16 u) {
    union { unsigned i; float f; } v; v.i = ((unsigned)u) << 16; return v.f;
}
__device__ inline u16 f2bf(float f) {
    union { float f; unsigned i; } v; v.f = f;
    unsigned r = v.i + 0x7fffu + ((v.i >> 16) & 1u);   // RNE
    return (u16)(r >> 16);
}
__device__ inline float sigm(float x) { return 1.0f / (1.0f + __expf(-x)); }
__device__ inline float tanh_(float x) {
    x = fminf(fmaxf(x, -30.0f), 30.0f);
    float e = __expf(-2.0f * x);
    return (1.0f - e) / (1.0f + e);
}
// NaN-proof clamp: fmaxf/fminf drop a NaN operand -> result always finite.
__device__ inline float zclamp(float x) { return fminf(fmaxf(x, -60.0f), 60.0f); }

// dual-dtype element read -> bf16 bits
__device__ inline u16 rd_bf(const void* p, size_t idx, int isbf) {
    return isbf ? ((const u16*)p)[idx] : f2bf(((const float*)p)[idx]);
}
__device__ inline float rd_f(const void* p, size_t idx, int isbf) {
    return isbf ? bf2f(((const u16*)p)[idx]) : ((const float*)p)[idx];
}

// ---------------- dtype probe ----------------
// x ~ N(0,1). If buffer is bf16: every u16 has exponent-field mostly in [118,131].
// If buffer is fp32: even-indexed u16s are low-mantissa bits ~ uniform -> ~5% in range.
__global__ void prep_probe(const void* x, int* flag) {
    if (blockIdx.x == 0 && threadIdx.x == 0) {
        const u16* p = (const u16*)x;
        int bfish = 0;
        for (int i = 0; i < 512; i += 2) {
            int e = (p[i] >> 7) & 0xFF;
            if (e >= 118 && e <= 131) ++bfish;
        }
        flag[0] = (bfish >= 128) ? 1 : 0;   // 1 = bf16 buffers, 0 = fp32 buffers
    }
}

// ---------------- prep kernels ----------------

__global__ void prep_misc(const void* b0, const void* b1, const void* b2, const void* b3,
                          float* __restrict__ bias, const void* h0,
                          u16* __restrict__ hbf, const int* __restrict__ flag) {
    const int isbf = flag[0];
    int i = blockIdx.x * 256 + threadIdx.x;
    if (i < 4096) {
        int g = i >> 10, n = i & 1023;
        const void* bp = (g == 0) ? b0 : (g == 1) ? b1 : (g == 2) ? b2 : b3;
        bias[i] = rd_f(bp, n, isbf);
    }
    int j = i - 4096;
    if (j >= 0 && j < B_ * H_) hbf[j] = rd_bf(h0, j, isbf);
}

// Ut[(g*1024+n)*1024 + k] = U_g[k*1024 + n]
__global__ void prep_ut(const void* u0, const void* u1, const void* u2, const void* u3,
                        u16* __restrict__ Ut, const int* __restrict__ flag) {
    const int isbf = flag[0];
    int idx = blockIdx.x * 256 + threadIdx.x;          // [4][128][1024]
    int g  = idx >> 17;
    int k8 = (idx >> 10) & 127;
    int n  = idx & 1023;
    const void* Ug = (g == 0) ? u0 : (g == 1) ? u1 : (g == 2) ? u2 : u3;
    int k0 = k8 * 8;
    union { u16 a[8]; short8 v; } t;
#pragma unroll
    for (int j = 0; j < 8; ++j) t.a[j] = rd_bf(Ug, (size_t)(k0 + j) * 1024 + n, isbf);
    *(short8*)(Ut + ((size_t)(g * 1024 + n) * 1024 + k0)) = t.v;
}

// Vp[((g*64+nb)*32+ks)*64+lane][8] = V_g[k][n], n=nb*16+(lane&15), k=ks*32+(lane>>4)*8+j
__global__ void prep_vp(const void* v0, const void* v1, const void* v2, const void* v3,
                        u16* __restrict__ Vp, const int* __restrict__ flag) {
    const int isbf = flag[0];
    int idx = blockIdx.x * 256 + threadIdx.x;          // [4][64][32][64]
    int lane = idx & 63;
    int ks = (idx >> 6) & 31;
    int nb = (idx >> 11) & 63;
    int g  = idx >> 17;
    const void* Vg = (g == 0) ? v0 : (g == 1) ? v1 : (g == 2) ? v2 : v3;
    int n  = nb * 16 + (lane & 15);
    int kb = ks * 32 + (lane >> 4) * 8;
    union { u16 a[8]; short8 v; } t;
#pragma unroll
    for (int j = 0; j < 8; ++j) t.a[j] = rd_bf(Vg, (size_t)(kb + j) * 1024 + n, isbf);
    *(short8*)(Vp + (size_t)idx * 8) = t.v;
}

// ---------------- phase 1: xu = x @ U + b  (bf16 out, [s][b][4096]) ----------------

__global__ __launch_bounds__(256) void gemm_xu(
    const void* __restrict__ xv, const u16* __restrict__ Ut,
    const float* __restrict__ bias, u16* __restrict__ xu,
    const int* __restrict__ flag) {
    const int isbf = flag[0];
    const int bx = blockIdx.x;
    const int m0 = (bx & 127) * 128;
    const int n0 = (bx >> 7) * 128;
    const int tid = threadIdx.x;
    const int w = tid >> 6, lane = tid & 63;
    const int lm = lane & 15, q = lane >> 4;
    const int r4 = lane >> 2, c4 = lane & 3;

    __shared__ __attribute__((aligned(16))) u16 As[128 * 32];
    __shared__ __attribute__((aligned(16))) u16 Bs[128 * 32];

    const int mb = (w >> 1) * 64, nbL = (w & 1) * 64;
    f32x4 acc[4][4] = {};

    for (int k0 = 0; k0 < 1024; k0 += 32) {
        __syncthreads();
#pragma unroll
        for (int i2 = 0; i2 < 2; ++i2) {
            const int i = w * 2 + i2;
            const size_t aoff = (size_t)(m0 + i * 16 + r4) * 1024 + k0 + c4 * 8;
            if (isbf) {
                const u16* ga = (const u16*)xv + aoff;
                __builtin_amdgcn_global_load_lds((const __attribute__((address_space(1))) void*)ga,
                                                 (__attribute__((address_space(3))) void*)(As + i * 512),
                                                 16, 0, 0);
            } else {
                const float* ga = (const float*)xv + aoff;
                f32x4 f0 = *(const f32x4*)ga;
                f32x4 f1 = *(const f32x4*)(ga + 4);
                union { u16 a[8]; short8 v; } t;
#pragma unroll
                for (int j = 0; j < 4; ++j) { t.a[j] = f2bf(f0[j]); t.a[4 + j] = f2bf(f1[j]); }
                *(short8*)(As + i * 512 + lane * 8) = t.v;
            }
            const u16* gb = Ut + (size_t)(n0 + i * 16 + r4) * 1024 + k0 + c4 * 8;
            __builtin_amdgcn_global_load_lds((const __attribute__((address_space(1))) void*)gb,
                                             (__attribute__((address_space(3))) void*)(Bs + i * 512),
                                             16, 0, 0);
        }
        __syncthreads();

        short8 af[4], bf[4];
#pragma unroll
        for (int mt = 0; mt < 4; ++mt)
            af[mt] = *(const short8*)(As + (mb + mt * 16 + lm) * 32 + q * 8);
#pragma unroll
        for (int nt = 0; nt < 4; ++nt)
            bf[nt] = *(const short8*)(Bs + (nbL + nt * 16 + lm) * 32 + q * 8);
#pragma unroll
        for (int mt = 0; mt < 4; ++mt)
#pragma unroll
            for (int nt = 0; nt < 4; ++nt)
                acc[mt][nt] = __builtin_amdgcn_mfma_f32_16x16x32_bf16(af[mt], bf[nt], acc[mt][nt], 0, 0, 0);
    }

#pragma unroll
    for (int mt = 0; mt < 4; ++mt) {
#pragma unroll
        for (int nt = 0; nt < 4; ++nt) {
            const int ng = n0 + nbL + nt * 16 + lm;
            const float bv = bias[ng];
#pragma unroll
            for (int r = 0; r < 4; ++r) {
                const int m = m0 + mb + mt * 16 + q * 4 + r;   // m = b*512 + s
                const int s = m & 511, b = m >> 9;
                xu[(size_t)(s * 32 + b) * 4096 + ng] = f2bf(acc[mt][nt][r] + bv);
            }
        }
    }
}

// ---------------- phase 2: persistent recurrence ----------------
// 64 WGs x 256 thr. WG nb owns cols [nb*16, nb*16+16) for all 4 gates.
// V held ENTIRELY in registers (128 VGPR/lane) for all 512 steps.
// h exchanged via plain loads/stores + __threadfence() around a
// device-scope release/acquire counter barrier (CG grid-sync pattern).

__global__ __launch_bounds__(256, 1) void lstm_rec(
    const u16* __restrict__ xu, const u16* __restrict__ Vp,
    const void* __restrict__ c0, u16* h_bf, void* outv, int* bar,
    const int* __restrict__ flag) {
    const int isbf = flag[0];
    const int nb = blockIdx.x;
    const int tid = threadIdx.x;
    const int w = tid >> 6;
    const int lane = tid & 63;
    const int lm = lane & 15;
    const int q = lane >> 4;

    __shared__ float part[4][4][2][16][16];   // [wave][gate][mt][row(b)][col(n)]

    const int em = tid >> 4;                   // batch row 0..15
    const int en = tid & 15;
    const int ncol = nb * 16 + en;             // col within gate

    float c_a = rd_f(c0, (size_t)em * H_ + ncol, isbf);
    float c_b = rd_f(c0, (size_t)(em + 16) * H_ + ncol, isbf);

    float* outf = (float*)outv;
    u16*   outh = (u16*)outv;

    // ---- load this wave's V fragments once; constant across all timesteps ----
    short8 bpre[4][8];
#pragma unroll
    for (int g = 0; g < 4; ++g)
#pragma unroll
        for (int kk = 0; kk < 8; ++kk) {
            const int ks = w * 8 + kk;
            bpre[g][kk] = *(const short8*)(Vp + ((((size_t)g * 64 + nb) * 32 + ks) * 64 + lane) * 8);
        }

    // ---- prefetch xu for t=0 ----
    u16 xva[4], xvb[4];
#pragma unroll
    for (int g = 0; g < 4; ++g) {
        xva[g] = xu[em * 4096 + g * 1024 + ncol];
        xvb[g] = xu[(em + 16) * 4096 + g * 1024 + ncol];
    }

    int par = 0;
#pragma unroll 1
    for (int t = 0; t < S_; ++t) {
        const u16* hb = h_bf + par * (B_ * H_);
        f32x4 acc[4][2] = {};
#pragma unroll
        for (int kk = 0; kk < 8; ++kk) {
            const int ks = w * 8 + kk;
            short8 a0 = *(const short8*)(hb + lm * H_ + ks * 32 + q * 8);
            short8 a1 = *(const short8*)(hb + (lm + 16) * H_ + ks * 32 + q * 8);
#pragma unroll
            for (int g = 0; g < 4; ++g) {
                acc[g][0] = __builtin_amdgcn_mfma_f32_16x16x32_bf16(a0, bpre[g][kk], acc[g][0], 0, 0, 0);
                acc[g][1] = __builtin_amdgcn_mfma_f32_16x16x32_bf16(a1, bpre[g][kk], acc[g][1], 0, 0, 0);
            }
        }

        // partials -> LDS
#pragma unroll
        for (int g = 0; g < 4; ++g)
#pragma unroll
            for (int mt = 0; mt < 2; ++mt)
#pragma unroll
                for (int r = 0; r < 4; ++r)
                    part[w][g][mt][q * 4 + r][lm] = acc[g][mt][r];
        __syncthreads();

        // reduce over waves (K-split) + elementwise
        float z_a[4], z_b[4];
#pragma unroll
        for (int g = 0; g < 4; ++g) {
            z_a[g] = zclamp(bf2f(xva[g]) + part[0][g][0][em][en] + part[1][g][0][em][en]
                                         + part[2][g][0][em][en] + part[3][g][0][em][en]);
            z_b[g] = zclamp(bf2f(xvb[g]) + part[0][g][1][em][en] + part[1][g][1][em][en]
                                         + part[2][g][1][em][en] + part[3][g][1][em][en]);
        }

        float ia = sigm(z_a[0]), fa = sigm(z_a[1]), ga = tanh_(z_a[2]), oa = sigm(z_a[3]);
        c_a = fa * c_a + ia * ga;
        float hA = oa * tanh_(c_a);
        float ib = sigm(z_b[0]), fb = sigm(z_b[1]), gb = tanh_(z_b[2]), ob = sigm(z_b[3]);
        c_b = fb * c_b + ib * gb;
        float hB = ob * tanh_(c_b);

        u16 hAb = f2bf(hA), hBb = f2bf(hB);
        u16* hn = h_bf + (par ^ 1) * (B_ * H_);
        hn[em * H_ + ncol]        = hAb;
        hn[(em + 16) * H_ + ncol] = hBb;

        const size_t oA = ((size_t)em * S_ + t) * H_ + ncol;
        const size_t oB = ((size_t)(em + 16) * S_ + t) * H_ + ncol;
        if (isbf) { outh[oA] = hAb; outh[oB] = hBb; }
        else      { outf[oA] = hA;  outf[oB] = hB;  }
        if (t == S_ - 1) {
            const size_t HS = (size_t)B_ * S_ * H_;
            const size_t hA_i = HS + (size_t)em * H_ + ncol;
            const size_t hB_i = HS + (size_t)(em + 16) * H_ + ncol;
            const size_t cA_i = HS + (size_t)B_ * H_ + (size_t)em * H_ + ncol;
            const size_t cB_i = HS + (size_t)B_ * H_ + (size_t)(em + 16) * H_ + ncol;
            if (isbf) { outh[hA_i] = hAb; outh[hB_i] = hBb; outh[cA_i] = f2bf(c_a); outh[cB_i] = f2bf(c_b); }
            else      { outf[hA_i] = hA;  outf[hB_i] = hB;  outf[cA_i] = c_a;       outf[cB_i] = c_b;       }
        }

        // prefetch xu for t+1 (wraps harmlessly at the end)
        {
            const u16* xt = xu + (size_t)((t + 1) & (S_ - 1)) * (B_ * 4 * H_);
#pragma unroll
            for (int g = 0; g < 4; ++g) {
                xva[g] = xt[em * 4096 + g * 1024 + ncol];
                xvb[g] = xt[(em + 16) * 4096 + g * 1024 + ncol];
            }
        }

        // --- grid barrier with agent-scope fences ---
        __threadfence();      // writer: drain h stores, L2 writeback
        __syncthreads();
        if (tid == 0) {
            __hip_atomic_fetch_add(&bar[0], 1, __ATOMIC_RELEASE, __HIP_MEMORY_SCOPE_AGENT);
            const int target = NBLK * (t + 1);
            while (__hip_atomic_load(&bar[0], __ATOMIC_ACQUIRE, __HIP_MEMORY_SCOPE_AGENT) < target)
                __builtin_amdgcn_s_sleep(1);
        }
        __syncthreads();
        __threadfence();      // reader: invalidate stale caches before h loads
        par ^= 1;
    }
}

// ---------------- host ----------------

extern "C" void kernel_launch(void* const* d_in, const int* in_sizes, int n_in,
                              void* d_out, int out_size, void* d_ws, size_t ws_size,
                              hipStream_t stream) {
    (void)in_sizes; (void)n_in; (void)out_size;
    if (ws_size < WS_NEED) return;   // diagnostic: out stays 0 -> absmax ~0.89 signature
    const void* x  = d_in[0];
    const void* h0 = d_in[1];
    const void* c0 = d_in[2];
    const void* U0 = d_in[3],  *V0 = d_in[4],  *bb0 = d_in[5];
    const void* U1 = d_in[6],  *V1 = d_in[7],  *bb1 = d_in[8];
    const void* U2 = d_in[9],  *V2 = d_in[10], *bb2 = d_in[11];
    const void* U3 = d_in[12], *V3 = d_in[13], *bb3 = d_in[14];

    char* ws = (char*)d_ws;
    int*   bar  = (int*)(ws + OFF_BAR);
    int*   flag = (int*)(ws + OFF_BAR + 64);
    u16*   hbf  = (u16*)(ws + OFF_HBF);
    float* bias = (float*)(ws + OFF_BIAS);
    u16*   Ut   = (u16*)(ws + OFF_UT);
    u16*   Vp   = (u16*)(ws + OFF_VP);
    u16*   xu   = (u16*)(ws + OFF_XU);

    hipMemsetAsync(bar, 0, 256, stream);
    prep_probe<<<dim3(1), dim3(64), 0, stream>>>(x, flag);
    prep_misc<<<dim3(144), dim3(256), 0, stream>>>(bb0, bb1, bb2, bb3, bias, h0, hbf, flag);
    prep_ut<<<dim3(2048), dim3(256), 0, stream>>>(U0, U1, U2, U3, Ut, flag);
    prep_vp<<<dim3(2048), dim3(256), 0, stream>>>(V0, V1, V2, V3, Vp, flag);
    gemm_xu<<<dim3(4096), dim3(256), 0, stream>>>(x, Ut, bias, xu, flag);
    lstm_rec<<<dim3(NBLK), dim3(256), 0, stream>>>(xu, Vp, c0, hbf, (void*)d_out, bar, flag);
}

// Round 4
// 5110.146 us; speedup vs baseline: 1.7619x; 1.7619x over previous
//
#include <hip/hip_runtime.h>
#include <stdint.h>

typedef unsigned short u16;
typedef unsigned long long u64;
typedef __attribute__((ext_vector_type(8))) short short8;
typedef __attribute__((ext_vector_type(4))) float f32x4;

#define B_ 32
#define S_ 512
#define H_ 1024
#define NBLK 64   // recurrence workgroups (<=256 CUs -> co-resident, spin barrier safe)

// ---- workspace layout (bytes), total ~144.2 MiB ----
static const size_t OFF_BAR  = 0;                         // barrier counter + dtype flag
static const size_t OFF_HBF  = 256;                       // h double buffer: 2*32*1024*2
static const size_t OFF_BIAS = OFF_HBF + 131072 + 256;    // fp32[4096]
static const size_t OFF_UT   = OFF_BIAS + 16384;          // U^T bf16 [4096][1024]
static const size_t OFF_VP   = OFF_UT + 8388608;          // V fragment-permuted bf16
static const size_t OFF_XU   = OFF_VP + 8388608;          // xu bf16 [512][32][4096]
static const size_t WS_NEED  = OFF_XU + (size_t)S_ * B_ * 4 * H_ * 2;

__device__ inline float bf2f(u16 u) {
    union { unsigned i; float f; } v; v.i = ((unsigned)u) << 16; return v.f;
}
__device__ inline u16 f2bf(float f) {
    union { float f; unsigned i; } v; v.f = f;
    unsigned r = v.i + 0x7fffu + ((v.i >> 16) & 1u);   // RNE
    return (u16)(r >> 16);
}
__device__ inline float sigm(float x) { return 1.0f / (1.0f + __expf(-x)); }
__device__ inline float tanh_(float x) {
    x = fminf(fmaxf(x, -30.0f), 30.0f);
    float e = __expf(-2.0f * x);
    return (1.0f - e) / (1.0f + e);
}
// NaN-proof clamp: fmaxf/fminf drop a NaN operand -> result always finite.
__device__ inline float zclamp(float x) { return fminf(fmaxf(x, -60.0f), 60.0f); }

// dual-dtype element read -> bf16 bits
__device__ inline u16 rd_bf(const void* p, size_t idx, int isbf) {
    return isbf ? ((const u16*)p)[idx] : f2bf(((const float*)p)[idx]);
}
__device__ inline float rd_f(const void* p, size_t idx, int isbf) {
    return isbf ? bf2f(((const u16*)p)[idx]) : ((const float*)p)[idx];
}

// ---------------- dtype probe ----------------
// x ~ N(0,1). If buffer is bf16: every u16 has exponent-field mostly in [118,131].
// If buffer is fp32: even-indexed u16s are low-mantissa bits ~ uniform -> ~5% in range.
__global__ void prep_probe(const void* x, int* flag) {
    if (blockIdx.x == 0 && threadIdx.x == 0) {
        const u16* p = (const u16*)x;
        int bfish = 0;
        for (int i = 0; i < 512; i += 2) {
            int e = (p[i] >> 7) & 0xFF;
            if (e >= 118 && e <= 131) ++bfish;
        }
        flag[0] = (bfish >= 128) ? 1 : 0;   // 1 = bf16 buffers, 0 = fp32 buffers
    }
}

// ---------------- prep kernels ----------------

__global__ void prep_misc(const void* b0, const void* b1, const void* b2, const void* b3,
                          float* __restrict__ bias, const void* h0,
                          u16* __restrict__ hbf, const int* __restrict__ flag) {
    const int isbf = flag[0];
    int i = blockIdx.x * 256 + threadIdx.x;
    if (i < 4096) {
        int g = i >> 10, n = i & 1023;
        const void* bp = (g == 0) ? b0 : (g == 1) ? b1 : (g == 2) ? b2 : b3;
        bias[i] = rd_f(bp, n, isbf);
    }
    int j = i - 4096;
    if (j >= 0 && j < B_ * H_) hbf[j] = rd_bf(h0, j, isbf);
}

// Ut[(g*1024+n)*1024 + k] = U_g[k*1024 + n]
__global__ void prep_ut(const void* u0, const void* u1, const void* u2, const void* u3,
                        u16* __restrict__ Ut, const int* __restrict__ flag) {
    const int isbf = flag[0];
    int idx = blockIdx.x * 256 + threadIdx.x;          // [4][128][1024]
    int g  = idx >> 17;
    int k8 = (idx >> 10) & 127;
    int n  = idx & 1023;
    const void* Ug = (g == 0) ? u0 : (g == 1) ? u1 : (g == 2) ? u2 : u3;
    int k0 = k8 * 8;
    union { u16 a[8]; short8 v; } t;
#pragma unroll
    for (int j = 0; j < 8; ++j) t.a[j] = rd_bf(Ug, (size_t)(k0 + j) * 1024 + n, isbf);
    *(short8*)(Ut + ((size_t)(g * 1024 + n) * 1024 + k0)) = t.v;
}

// Vp[((g*64+nb)*32+ks)*64+lane][8] = V_g[k][n], n=nb*16+(lane&15), k=ks*32+(lane>>4)*8+j
__global__ void prep_vp(const void* v0, const void* v1, const void* v2, const void* v3,
                        u16* __restrict__ Vp, const int* __restrict__ flag) {
    const int isbf = flag[0];
    int idx = blockIdx.x * 256 + threadIdx.x;          // [4][64][32][64]
    int lane = idx & 63;
    int ks = (idx >> 6) & 31;
    int nb = (idx >> 11) & 63;
    int g  = idx >> 17;
    const void* Vg = (g == 0) ? v0 : (g == 1) ? v1 : (g == 2) ? v2 : v3;
    int n  = nb * 16 + (lane & 15);
    int kb = ks * 32 + (lane >> 4) * 8;
    union { u16 a[8]; short8 v; } t;
#pragma unroll
    for (int j = 0; j < 8; ++j) t.a[j] = rd_bf(Vg, (size_t)(kb + j) * 1024 + n, isbf);
    *(short8*)(Vp + (size_t)idx * 8) = t.v;
}

// ---------------- phase 1: xu = x @ U + b  (bf16 out, [s][b][4096]) ----------------

__global__ __launch_bounds__(256) void gemm_xu(
    const void* __restrict__ xv, const u16* __restrict__ Ut,
    const float* __restrict__ bias, u16* __restrict__ xu,
    const int* __restrict__ flag) {
    const int isbf = flag[0];
    const int bx = blockIdx.x;
    const int m0 = (bx & 127) * 128;
    const int n0 = (bx >> 7) * 128;
    const int tid = threadIdx.x;
    const int w = tid >> 6, lane = tid & 63;
    const int lm = lane & 15, q = lane >> 4;
    const int r4 = lane >> 2, c4 = lane & 3;

    __shared__ __attribute__((aligned(16))) u16 As[128 * 32];
    __shared__ __attribute__((aligned(16))) u16 Bs[128 * 32];

    const int mb = (w >> 1) * 64, nbL = (w & 1) * 64;
    f32x4 acc[4][4] = {};

    for (int k0 = 0; k0 < 1024; k0 += 32) {
        __syncthreads();
#pragma unroll
        for (int i2 = 0; i2 < 2; ++i2) {
            const int i = w * 2 + i2;
            const size_t aoff = (size_t)(m0 + i * 16 + r4) * 1024 + k0 + c4 * 8;
            if (isbf) {
                const u16* ga = (const u16*)xv + aoff;
                __builtin_amdgcn_global_load_lds((const __attribute__((address_space(1))) void*)ga,
                                                 (__attribute__((address_space(3))) void*)(As + i * 512),
                                                 16, 0, 0);
            } else {
                const float* ga = (const float*)xv + aoff;
                f32x4 f0 = *(const f32x4*)ga;
                f32x4 f1 = *(const f32x4*)(ga + 4);
                union { u16 a[8]; short8 v; } t;
#pragma unroll
                for (int j = 0; j < 4; ++j) { t.a[j] = f2bf(f0[j]); t.a[4 + j] = f2bf(f1[j]); }
                *(short8*)(As + i * 512 + lane * 8) = t.v;
            }
            const u16* gb = Ut + (size_t)(n0 + i * 16 + r4) * 1024 + k0 + c4 * 8;
            __builtin_amdgcn_global_load_lds((const __attribute__((address_space(1))) void*)gb,
                                             (__attribute__((address_space(3))) void*)(Bs + i * 512),
                                             16, 0, 0);
        }
        __syncthreads();

        short8 af[4], bf[4];
#pragma unroll
        for (int mt = 0; mt < 4; ++mt)
            af[mt] = *(const short8*)(As + (mb + mt * 16 + lm) * 32 + q * 8);
#pragma unroll
        for (int nt = 0; nt < 4; ++nt)
            bf[nt] = *(const short8*)(Bs + (nbL + nt * 16 + lm) * 32 + q * 8);
#pragma unroll
        for (int mt = 0; mt < 4; ++mt)
#pragma unroll
            for (int nt = 0; nt < 4; ++nt)
                acc[mt][nt] = __builtin_amdgcn_mfma_f32_16x16x32_bf16(af[mt], bf[nt], acc[mt][nt], 0, 0, 0);
    }

#pragma unroll
    for (int mt = 0; mt < 4; ++mt) {
#pragma unroll
        for (int nt = 0; nt < 4; ++nt) {
            const int ng = n0 + nbL + nt * 16 + lm;
            const float bv = bias[ng];
#pragma unroll
            for (int r = 0; r < 4; ++r) {
                const int m = m0 + mb + mt * 16 + q * 4 + r;   // m = b*512 + s
                const int s = m & 511, b = m >> 9;
                xu[(size_t)(s * 32 + b) * 4096 + ng] = f2bf(acc[mt][nt][r] + bv);
            }
        }
    }
}

// ---------------- phase 2: persistent recurrence ----------------
// 64 WGs x 256 thr. WG nb owns cols [nb*16, nb*16+16) for all 4 gates.
// V held ENTIRELY in registers (128 VGPR/lane) for all 512 steps.
// h round-trips through the LLC via RELAXED AGENT-SCOPE atomics (sc1:
// bypass non-coherent per-XCD L1/L2). No __threadfence -> no L2
// writeback/invalidate per step (that was round 3's 16.6 us/step cost).
// Ordering: h stores (sc1) -> RELEASE counter add (drains vmcnt) ->
// ACQUIRE spin -> sc1 h loads. LLC is the single coherence point.

__global__ __launch_bounds__(256, 1) void lstm_rec(
    const u16* __restrict__ xu, const u16* __restrict__ Vp,
    const void* __restrict__ c0, u16* h_bf, void* outv, int* bar,
    const int* __restrict__ flag) {
    const int isbf = flag[0];
    const int nb = blockIdx.x;
    const int tid = threadIdx.x;
    const int w = tid >> 6;
    const int lane = tid & 63;
    const int lm = lane & 15;
    const int q = lane >> 4;

    __shared__ float part[4][4][2][16][16];   // [wave][gate][mt][row(b)][col(n)]

    const int em = tid >> 4;                   // batch row 0..15
    const int en = tid & 15;
    const int ncol = nb * 16 + en;             // col within gate

    float c_a = rd_f(c0, (size_t)em * H_ + ncol, isbf);
    float c_b = rd_f(c0, (size_t)(em + 16) * H_ + ncol, isbf);

    float* outf = (float*)outv;
    u16*   outh = (u16*)outv;

    // ---- load this wave's V fragments once; constant across all timesteps ----
    short8 bpre[4][8];
#pragma unroll
    for (int g = 0; g < 4; ++g)
#pragma unroll
        for (int kk = 0; kk < 8; ++kk) {
            const int ks = w * 8 + kk;
            bpre[g][kk] = *(const short8*)(Vp + ((((size_t)g * 64 + nb) * 32 + ks) * 64 + lane) * 8);
        }

    // ---- prefetch xu for t=0 ----
    u16 xva[4], xvb[4];
#pragma unroll
    for (int g = 0; g < 4; ++g) {
        xva[g] = xu[em * 4096 + g * 1024 + ncol];
        xvb[g] = xu[(em + 16) * 4096 + g * 1024 + ncol];
    }

    int par = 0;
#pragma unroll 1
    for (int t = 0; t < S_; ++t) {
        const u16* hb = h_bf + par * (B_ * H_);
        f32x4 acc[4][2] = {};
#pragma unroll
        for (int kk = 0; kk < 8; ++kk) {
            const int ks = w * 8 + kk;
            union { u64 d[2]; short8 v; } a0u, a1u;
            const u64* p0 = (const u64*)(hb + lm * H_ + ks * 32 + q * 8);
            const u64* p1 = (const u64*)(hb + (lm + 16) * H_ + ks * 32 + q * 8);
            a0u.d[0] = __hip_atomic_load(p0,     __ATOMIC_RELAXED, __HIP_MEMORY_SCOPE_AGENT);
            a0u.d[1] = __hip_atomic_load(p0 + 1, __ATOMIC_RELAXED, __HIP_MEMORY_SCOPE_AGENT);
            a1u.d[0] = __hip_atomic_load(p1,     __ATOMIC_RELAXED, __HIP_MEMORY_SCOPE_AGENT);
            a1u.d[1] = __hip_atomic_load(p1 + 1, __ATOMIC_RELAXED, __HIP_MEMORY_SCOPE_AGENT);
#pragma unroll
            for (int g = 0; g < 4; ++g) {
                acc[g][0] = __builtin_amdgcn_mfma_f32_16x16x32_bf16(a0u.v, bpre[g][kk], acc[g][0], 0, 0, 0);
                acc[g][1] = __builtin_amdgcn_mfma_f32_16x16x32_bf16(a1u.v, bpre[g][kk], acc[g][1], 0, 0, 0);
            }
        }

        // partials -> LDS
#pragma unroll
        for (int g = 0; g < 4; ++g)
#pragma unroll
            for (int mt = 0; mt < 2; ++mt)
#pragma unroll
                for (int r = 0; r < 4; ++r)
                    part[w][g][mt][q * 4 + r][lm] = acc[g][mt][r];
        __syncthreads();

        // reduce over waves (K-split) + elementwise
        float z_a[4], z_b[4];
#pragma unroll
        for (int g = 0; g < 4; ++g) {
            z_a[g] = zclamp(bf2f(xva[g]) + part[0][g][0][em][en] + part[1][g][0][em][en]
                                         + part[2][g][0][em][en] + part[3][g][0][em][en]);
            z_b[g] = zclamp(bf2f(xvb[g]) + part[0][g][1][em][en] + part[1][g][1][em][en]
                                         + part[2][g][1][em][en] + part[3][g][1][em][en]);
        }

        float ia = sigm(z_a[0]), fa = sigm(z_a[1]), ga = tanh_(z_a[2]), oa = sigm(z_a[3]);
        c_a = fa * c_a + ia * ga;
        float hA = oa * tanh_(c_a);
        float ib = sigm(z_b[0]), fb = sigm(z_b[1]), gb = tanh_(z_b[2]), ob = sigm(z_b[3]);
        c_b = fb * c_b + ib * gb;
        float hB = ob * tanh_(c_b);

        u16 hAb = f2bf(hA), hBb = f2bf(hB);
        u16* hn = h_bf + (par ^ 1) * (B_ * H_);
        __hip_atomic_store(&hn[em * H_ + ncol],        hAb, __ATOMIC_RELAXED, __HIP_MEMORY_SCOPE_AGENT);
        __hip_atomic_store(&hn[(em + 16) * H_ + ncol], hBb, __ATOMIC_RELAXED, __HIP_MEMORY_SCOPE_AGENT);

        const size_t oA = ((size_t)em * S_ + t) * H_ + ncol;
        const size_t oB = ((size_t)(em + 16) * S_ + t) * H_ + ncol;
        if (isbf) { outh[oA] = hAb; outh[oB] = hBb; }
        else      { outf[oA] = hA;  outf[oB] = hB;  }
        if (t == S_ - 1) {
            const size_t HS = (size_t)B_ * S_ * H_;
            const size_t hA_i = HS + (size_t)em * H_ + ncol;
            const size_t hB_i = HS + (size_t)(em + 16) * H_ + ncol;
            const size_t cA_i = HS + (size_t)B_ * H_ + (size_t)em * H_ + ncol;
            const size_t cB_i = HS + (size_t)B_ * H_ + (size_t)(em + 16) * H_ + ncol;
            if (isbf) { outh[hA_i] = hAb; outh[hB_i] = hBb; outh[cA_i] = f2bf(c_a); outh[cB_i] = f2bf(c_b); }
            else      { outf[hA_i] = hA;  outf[hB_i] = hB;  outf[cA_i] = c_a;       outf[cB_i] = c_b;       }
        }

        // prefetch xu for t+1 (wraps harmlessly at the end)
        {
            const u16* xt = xu + (size_t)((t + 1) & (S_ - 1)) * (B_ * 4 * H_);
#pragma unroll
            for (int g = 0; g < 4; ++g) {
                xva[g] = xt[em * 4096 + g * 1024 + ncol];
                xvb[g] = xt[(em + 16) * 4096 + g * 1024 + ncol];
            }
        }

        // --- grid barrier (no cache maintenance; sc1 h traffic is LLC-coherent) ---
        __syncthreads();
        if (tid == 0) {
            __hip_atomic_fetch_add(&bar[0], 1, __ATOMIC_RELEASE, __HIP_MEMORY_SCOPE_AGENT);
            const int target = NBLK * (t + 1);
            while (__hip_atomic_load(&bar[0], __ATOMIC_ACQUIRE, __HIP_MEMORY_SCOPE_AGENT) < target)
                __builtin_amdgcn_s_sleep(1);
        }
        __syncthreads();
        par ^= 1;
    }
}

// ---------------- host ----------------

extern "C" void kernel_launch(void* const* d_in, const int* in_sizes, int n_in,
                              void* d_out, int out_size, void* d_ws, size_t ws_size,
                              hipStream_t stream) {
    (void)in_sizes; (void)n_in; (void)out_size;
    if (ws_size < WS_NEED) return;   // diagnostic: out stays 0 -> absmax ~0.89 signature
    const void* x  = d_in[0];
    const void* h0 = d_in[1];
    const void* c0 = d_in[2];
    const void* U0 = d_in[3],  *V0 = d_in[4],  *bb0 = d_in[5];
    const void* U1 = d_in[6],  *V1 = d_in[7],  *bb1 = d_in[8];
    const void* U2 = d_in[9],  *V2 = d_in[10], *bb2 = d_in[11];
    const void* U3 = d_in[12], *V3 = d_in[13], *bb3 = d_in[14];

    char* ws = (char*)d_ws;
    int*   bar  = (int*)(ws + OFF_BAR);
    int*   flag = (int*)(ws + OFF_BAR + 64);
    u16*   hbf  = (u16*)(ws + OFF_HBF);
    float* bias = (float*)(ws + OFF_BIAS);
    u16*   Ut   = (u16*)(ws + OFF_UT);
    u16*   Vp   = (u16*)(ws + OFF_VP);
    u16*   xu   = (u16*)(ws + OFF_XU);

    hipMemsetAsync(bar, 0, 256, stream);
    prep_probe<<<dim3(1), dim3(64), 0, stream>>>(x, flag);
    prep_misc<<<dim3(144), dim3(256), 0, stream>>>(bb0, bb1, bb2, bb3, bias, h0, hbf, flag);
    prep_ut<<<dim3(2048), dim3(256), 0, stream>>>(U0, U1, U2, U3, Ut, flag);
    prep_vp<<<dim3(2048), dim3(256), 0, stream>>>(V0, V1, V2, V3, Vp, flag);
    gemm_xu<<<dim3(4096), dim3(256), 0, stream>>>(x, Ut, bias, xu, flag);
    lstm_rec<<<dim3(NBLK), dim3(256), 0, stream>>>(xu, Vp, c0, hbf, (void*)d_out, bar, flag);
}

// Round 5
// 3860.044 us; speedup vs baseline: 2.3325x; 1.3239x over previous
//
#include <hip/hip_runtime.h>
#include <stdint.h>

typedef unsigned short u16;
typedef unsigned long long u64;
typedef __attribute__((ext_vector_type(8))) short short8;
typedef __attribute__((ext_vector_type(4))) float f32x4;

#define B_ 32
#define S_ 512
#define H_ 1024
#define NBLK 64   // recurrence workgroups (<=256 CUs -> co-resident, spin barrier safe)

// ---- workspace layout (bytes), total ~144.2 MiB ----
static const size_t OFF_BAR  = 0;                         // barrier counter + dtype flag
static const size_t OFF_HBF  = 256;                       // h double buffer: 2*32*1024*2
static const size_t OFF_BIAS = OFF_HBF + 131072 + 256;    // fp32[4096]
static const size_t OFF_UT   = OFF_BIAS + 16384;          // U^T bf16 [4096][1024]
static const size_t OFF_VP   = OFF_UT + 8388608;          // V fragment-permuted bf16
static const size_t OFF_XU   = OFF_VP + 8388608;          // xu bf16 [512][32][4096]
static const size_t WS_NEED  = OFF_XU + (size_t)S_ * B_ * 4 * H_ * 2;

__device__ inline float bf2f(u16 u) {
    union { unsigned i; float f; } v; v.i = ((unsigned)u) << 16; return v.f;
}
__device__ inline u16 f2bf(float f) {
    union { float f; unsigned i; } v; v.f = f;
    unsigned r = v.i + 0x7fffu + ((v.i >> 16) & 1u);   // RNE
    return (u16)(r >> 16);
}
__device__ inline float sigm(float x) { return 1.0f / (1.0f + __expf(-x)); }
__device__ inline float tanh_(float x) {
    x = fminf(fmaxf(x, -30.0f), 30.0f);
    float e = __expf(-2.0f * x);
    return (1.0f - e) / (1.0f + e);
}
// NaN-proof clamp: fmaxf/fminf drop a NaN operand -> result always finite.
__device__ inline float zclamp(float x) { return fminf(fmaxf(x, -60.0f), 60.0f); }

// dual-dtype element read -> bf16 bits
__device__ inline u16 rd_bf(const void* p, size_t idx, int isbf) {
    return isbf ? ((const u16*)p)[idx] : f2bf(((const float*)p)[idx]);
}
__device__ inline float rd_f(const void* p, size_t idx, int isbf) {
    return isbf ? bf2f(((const u16*)p)[idx]) : ((const float*)p)[idx];
}

// ---------------- dtype probe ----------------
// x ~ N(0,1). If buffer is bf16: every u16 has exponent-field mostly in [118,131].
// If buffer is fp32: even-indexed u16s are low-mantissa bits ~ uniform -> ~5% in range.
__global__ void prep_probe(const void* x, int* flag) {
    if (blockIdx.x == 0 && threadIdx.x == 0) {
        const u16* p = (const u16*)x;
        int bfish = 0;
        for (int i = 0; i < 512; i += 2) {
            int e = (p[i] >> 7) & 0xFF;
            if (e >= 118 && e <= 131) ++bfish;
        }
        flag[0] = (bfish >= 128) ? 1 : 0;   // 1 = bf16 buffers, 0 = fp32 buffers
    }
}

// ---------------- prep kernels ----------------

__global__ void prep_misc(const void* b0, const void* b1, const void* b2, const void* b3,
                          float* __restrict__ bias, const void* h0,
                          u16* __restrict__ hbf, const int* __restrict__ flag) {
    const int isbf = flag[0];
    int i = blockIdx.x * 256 + threadIdx.x;
    if (i < 4096) {
        int g = i >> 10, n = i & 1023;
        const void* bp = (g == 0) ? b0 : (g == 1) ? b1 : (g == 2) ? b2 : b3;
        bias[i] = rd_f(bp, n, isbf);
    }
    int j = i - 4096;
    if (j >= 0 && j < B_ * H_) hbf[j] = rd_bf(h0, j, isbf);
}

// Ut[(g*1024+n)*1024 + k] = U_g[k*1024 + n]
__global__ void prep_ut(const void* u0, const void* u1, const void* u2, const void* u3,
                        u16* __restrict__ Ut, const int* __restrict__ flag) {
    const int isbf = flag[0];
    int idx = blockIdx.x * 256 + threadIdx.x;          // [4][128][1024]
    int g  = idx >> 17;
    int k8 = (idx >> 10) & 127;
    int n  = idx & 1023;
    const void* Ug = (g == 0) ? u0 : (g == 1) ? u1 : (g == 2) ? u2 : u3;
    int k0 = k8 * 8;
    union { u16 a[8]; short8 v; } t;
#pragma unroll
    for (int j = 0; j < 8; ++j) t.a[j] = rd_bf(Ug, (size_t)(k0 + j) * 1024 + n, isbf);
    *(short8*)(Ut + ((size_t)(g * 1024 + n) * 1024 + k0)) = t.v;
}

// Vp[((g*64+nb)*32+ks)*64+lane][8] = V_g[k][n], n=nb*16+(lane&15), k=ks*32+(lane>>4)*8+j
__global__ void prep_vp(const void* v0, const void* v1, const void* v2, const void* v3,
                        u16* __restrict__ Vp, const int* __restrict__ flag) {
    const int isbf = flag[0];
    int idx = blockIdx.x * 256 + threadIdx.x;          // [4][64][32][64]
    int lane = idx & 63;
    int ks = (idx >> 6) & 31;
    int nb = (idx >> 11) & 63;
    int g  = idx >> 17;
    const void* Vg = (g == 0) ? v0 : (g == 1) ? v1 : (g == 2) ? v2 : v3;
    int n  = nb * 16 + (lane & 15);
    int kb = ks * 32 + (lane >> 4) * 8;
    union { u16 a[8]; short8 v; } t;
#pragma unroll
    for (int j = 0; j < 8; ++j) t.a[j] = rd_bf(Vg, (size_t)(kb + j) * 1024 + n, isbf);
    *(short8*)(Vp + (size_t)idx * 8) = t.v;
}

// ---------------- phase 1: xu = x @ U + b  (bf16 out, [s][b][4096]) ----------------

__global__ __launch_bounds__(256) void gemm_xu(
    const void* __restrict__ xv, const u16* __restrict__ Ut,
    const float* __restrict__ bias, u16* __restrict__ xu,
    const int* __restrict__ flag) {
    const int isbf = flag[0];
    const int bx = blockIdx.x;
    const int m0 = (bx & 127) * 128;
    const int n0 = (bx >> 7) * 128;
    const int tid = threadIdx.x;
    const int w = tid >> 6, lane = tid & 63;
    const int lm = lane & 15, q = lane >> 4;
    const int r4 = lane >> 2, c4 = lane & 3;

    __shared__ __attribute__((aligned(16))) u16 As[128 * 32];
    __shared__ __attribute__((aligned(16))) u16 Bs[128 * 32];

    const int mb = (w >> 1) * 64, nbL = (w & 1) * 64;
    f32x4 acc[4][4] = {};

    for (int k0 = 0; k0 < 1024; k0 += 32) {
        __syncthreads();
#pragma unroll
        for (int i2 = 0; i2 < 2; ++i2) {
            const int i = w * 2 + i2;
            const size_t aoff = (size_t)(m0 + i * 16 + r4) * 1024 + k0 + c4 * 8;
            if (isbf) {
                const u16* ga = (const u16*)xv + aoff;
                __builtin_amdgcn_global_load_lds((const __attribute__((address_space(1))) void*)ga,
                                                 (__attribute__((address_space(3))) void*)(As + i * 512),
                                                 16, 0, 0);
            } else {
                const float* ga = (const float*)xv + aoff;
                f32x4 f0 = *(const f32x4*)ga;
                f32x4 f1 = *(const f32x4*)(ga + 4);
                union { u16 a[8]; short8 v; } t;
#pragma unroll
                for (int j = 0; j < 4; ++j) { t.a[j] = f2bf(f0[j]); t.a[4 + j] = f2bf(f1[j]); }
                *(short8*)(As + i * 512 + lane * 8) = t.v;
            }
            const u16* gb = Ut + (size_t)(n0 + i * 16 + r4) * 1024 + k0 + c4 * 8;
            __builtin_amdgcn_global_load_lds((const __attribute__((address_space(1))) void*)gb,
                                             (__attribute__((address_space(3))) void*)(Bs + i * 512),
                                             16, 0, 0);
        }
        __syncthreads();

        short8 af[4], bf[4];
#pragma unroll
        for (int mt = 0; mt < 4; ++mt)
            af[mt] = *(const short8*)(As + (mb + mt * 16 + lm) * 32 + q * 8);
#pragma unroll
        for (int nt = 0; nt < 4; ++nt)
            bf[nt] = *(const short8*)(Bs + (nbL + nt * 16 + lm) * 32 + q * 8);
#pragma unroll
        for (int mt = 0; mt < 4; ++mt)
#pragma unroll
            for (int nt = 0; nt < 4; ++nt)
                acc[mt][nt] = __builtin_amdgcn_mfma_f32_16x16x32_bf16(af[mt], bf[nt], acc[mt][nt], 0, 0, 0);
    }

#pragma unroll
    for (int mt = 0; mt < 4; ++mt) {
#pragma unroll
        for (int nt = 0; nt < 4; ++nt) {
            const int ng = n0 + nbL + nt * 16 + lm;
            const float bv = bias[ng];
#pragma unroll
            for (int r = 0; r < 4; ++r) {
                const int m = m0 + mb + mt * 16 + q * 4 + r;   // m = b*512 + s
                const int s = m & 511, b = m >> 9;
                xu[(size_t)(s * 32 + b) * 4096 + ng] = f2bf(acc[mt][nt][r] + bv);
            }
        }
    }
}

// ---------------- phase 2: persistent recurrence ----------------
// 64 WGs x 256 thr. WG nb owns cols [nb*16, nb*16+16) for all 4 gates.
// V held ENTIRELY in registers (128 VGPR/lane) for all 512 steps.
// h round-trips through the LLC via RELAXED agent-scope atomics (sc1:
// bypass non-coherent per-XCD L1/L2).
// Barrier atomics are ALSO RELAXED: release/acquire at agent scope lower
// to buffer_wbl2/buffer_inv on multi-XCD gfx950 (acquire was in the POLL
// LOOP -> L2 invalidated every poll; thats why round-4 FETCH_SIZE stayed
// 3x compulsory). Ordering is structural instead:
//   writer: sc1 h-stores -> __syncthreads (s_waitcnt vmcnt(0): stores
//           acked by LLC) -> relaxed counter add (reaches LLC after)
//   reader: relaxed poll sees all adds -> __syncthreads -> sc1 h-loads
//           (served by LLC; no stale cache exists to invalidate)

__global__ __launch_bounds__(256, 1) void lstm_rec(
    const u16* __restrict__ xu, const u16* __restrict__ Vp,
    const void* __restrict__ c0, u16* h_bf, void* outv, int* bar,
    const int* __restrict__ flag) {
    const int isbf = flag[0];
    const int nb = blockIdx.x;
    const int tid = threadIdx.x;
    const int w = tid >> 6;
    const int lane = tid & 63;
    const int lm = lane & 15;
    const int q = lane >> 4;

    __shared__ float part[4][4][2][16][16];   // [wave][gate][mt][row(b)][col(n)]

    const int em = tid >> 4;                   // batch row 0..15
    const int en = tid & 15;
    const int ncol = nb * 16 + en;             // col within gate

    float c_a = rd_f(c0, (size_t)em * H_ + ncol, isbf);
    float c_b = rd_f(c0, (size_t)(em + 16) * H_ + ncol, isbf);

    float* outf = (float*)outv;
    u16*   outh = (u16*)outv;

    // ---- load this wave's V fragments once; constant across all timesteps ----
    short8 bpre[4][8];
#pragma unroll
    for (int g = 0; g < 4; ++g)
#pragma unroll
        for (int kk = 0; kk < 8; ++kk) {
            const int ks = w * 8 + kk;
            bpre[g][kk] = *(const short8*)(Vp + ((((size_t)g * 64 + nb) * 32 + ks) * 64 + lane) * 8);
        }

    // ---- prefetch xu for t=0 ----
    u16 xva[4], xvb[4];
#pragma unroll
    for (int g = 0; g < 4; ++g) {
        xva[g] = xu[em * 4096 + g * 1024 + ncol];
        xvb[g] = xu[(em + 16) * 4096 + g * 1024 + ncol];
    }

    int par = 0;
#pragma unroll 1
    for (int t = 0; t < S_; ++t) {
        const u16* hb = h_bf + par * (B_ * H_);
        f32x4 acc[4][2] = {};
#pragma unroll
        for (int kk = 0; kk < 8; ++kk) {
            const int ks = w * 8 + kk;
            union { u64 d[2]; short8 v; } a0u, a1u;
            const u64* p0 = (const u64*)(hb + lm * H_ + ks * 32 + q * 8);
            const u64* p1 = (const u64*)(hb + (lm + 16) * H_ + ks * 32 + q * 8);
            a0u.d[0] = __hip_atomic_load(p0,     __ATOMIC_RELAXED, __HIP_MEMORY_SCOPE_AGENT);
            a0u.d[1] = __hip_atomic_load(p0 + 1, __ATOMIC_RELAXED, __HIP_MEMORY_SCOPE_AGENT);
            a1u.d[0] = __hip_atomic_load(p1,     __ATOMIC_RELAXED, __HIP_MEMORY_SCOPE_AGENT);
            a1u.d[1] = __hip_atomic_load(p1 + 1, __ATOMIC_RELAXED, __HIP_MEMORY_SCOPE_AGENT);
#pragma unroll
            for (int g = 0; g < 4; ++g) {
                acc[g][0] = __builtin_amdgcn_mfma_f32_16x16x32_bf16(a0u.v, bpre[g][kk], acc[g][0], 0, 0, 0);
                acc[g][1] = __builtin_amdgcn_mfma_f32_16x16x32_bf16(a1u.v, bpre[g][kk], acc[g][1], 0, 0, 0);
            }
        }

        // partials -> LDS
#pragma unroll
        for (int g = 0; g < 4; ++g)
#pragma unroll
            for (int mt = 0; mt < 2; ++mt)
#pragma unroll
                for (int r = 0; r < 4; ++r)
                    part[w][g][mt][q * 4 + r][lm] = acc[g][mt][r];
        __syncthreads();

        // reduce over waves (K-split) + elementwise
        float z_a[4], z_b[4];
#pragma unroll
        for (int g = 0; g < 4; ++g) {
            z_a[g] = zclamp(bf2f(xva[g]) + part[0][g][0][em][en] + part[1][g][0][em][en]
                                         + part[2][g][0][em][en] + part[3][g][0][em][en]);
            z_b[g] = zclamp(bf2f(xvb[g]) + part[0][g][1][em][en] + part[1][g][1][em][en]
                                         + part[2][g][1][em][en] + part[3][g][1][em][en]);
        }

        float ia = sigm(z_a[0]), fa = sigm(z_a[1]), ga = tanh_(z_a[2]), oa = sigm(z_a[3]);
        c_a = fa * c_a + ia * ga;
        float hA = oa * tanh_(c_a);
        float ib = sigm(z_b[0]), fb = sigm(z_b[1]), gb = tanh_(z_b[2]), ob = sigm(z_b[3]);
        c_b = fb * c_b + ib * gb;
        float hB = ob * tanh_(c_b);

        u16 hAb = f2bf(hA), hBb = f2bf(hB);
        u16* hn = h_bf + (par ^ 1) * (B_ * H_);
        __hip_atomic_store(&hn[em * H_ + ncol],        hAb, __ATOMIC_RELAXED, __HIP_MEMORY_SCOPE_AGENT);
        __hip_atomic_store(&hn[(em + 16) * H_ + ncol], hBb, __ATOMIC_RELAXED, __HIP_MEMORY_SCOPE_AGENT);

        const size_t oA = ((size_t)em * S_ + t) * H_ + ncol;
        const size_t oB = ((size_t)(em + 16) * S_ + t) * H_ + ncol;
        if (isbf) { outh[oA] = hAb; outh[oB] = hBb; }
        else      { outf[oA] = hA;  outf[oB] = hB;  }
        if (t == S_ - 1) {
            const size_t HS = (size_t)B_ * S_ * H_;
            const size_t hA_i = HS + (size_t)em * H_ + ncol;
            const size_t hB_i = HS + (size_t)(em + 16) * H_ + ncol;
            const size_t cA_i = HS + (size_t)B_ * H_ + (size_t)em * H_ + ncol;
            const size_t cB_i = HS + (size_t)B_ * H_ + (size_t)(em + 16) * H_ + ncol;
            if (isbf) { outh[hA_i] = hAb; outh[hB_i] = hBb; outh[cA_i] = f2bf(c_a); outh[cB_i] = f2bf(c_b); }
            else      { outf[hA_i] = hA;  outf[hB_i] = hB;  outf[cA_i] = c_a;       outf[cB_i] = c_b;       }
        }

        // prefetch xu for t+1 (wraps harmlessly at the end)
        {
            const u16* xt = xu + (size_t)((t + 1) & (S_ - 1)) * (B_ * 4 * H_);
#pragma unroll
            for (int g = 0; g < 4; ++g) {
                xva[g] = xt[em * 4096 + g * 1024 + ncol];
                xvb[g] = xt[(em + 16) * 4096 + g * 1024 + ncol];
            }
        }

        // --- grid barrier: all-relaxed (no wbl2/inv); ordering via vmcnt drain ---
        __syncthreads();   // s_waitcnt vmcnt(0): sc1 h-stores acked by LLC before add
        if (tid == 0) {
            __hip_atomic_fetch_add(&bar[0], 1, __ATOMIC_RELAXED, __HIP_MEMORY_SCOPE_AGENT);
            const int target = NBLK * (t + 1);
            while (__hip_atomic_load(&bar[0], __ATOMIC_RELAXED, __HIP_MEMORY_SCOPE_AGENT) < target)
                __builtin_amdgcn_s_sleep(1);
        }
        __syncthreads();
        par ^= 1;
    }
}

// ---------------- host ----------------

extern "C" void kernel_launch(void* const* d_in, const int* in_sizes, int n_in,
                              void* d_out, int out_size, void* d_ws, size_t ws_size,
                              hipStream_t stream) {
    (void)in_sizes; (void)n_in; (void)out_size;
    if (ws_size < WS_NEED) return;   // diagnostic: out stays 0 -> absmax ~0.89 signature
    const void* x  = d_in[0];
    const void* h0 = d_in[1];
    const void* c0 = d_in[2];
    const void* U0 = d_in[3],  *V0 = d_in[4],  *bb0 = d_in[5];
    const void* U1 = d_in[6],  *V1 = d_in[7],  *bb1 = d_in[8];
    const void* U2 = d_in[9],  *V2 = d_in[10], *bb2 = d_in[11];
    const void* U3 = d_in[12], *V3 = d_in[13], *bb3 = d_in[14];

    char* ws = (char*)d_ws;
    int*   bar  = (int*)(ws + OFF_BAR);
    int*   flag = (int*)(ws + OFF_BAR + 64);
    u16*   hbf  = (u16*)(ws + OFF_HBF);
    float* bias = (float*)(ws + OFF_BIAS);
    u16*   Ut   = (u16*)(ws + OFF_UT);
    u16*   Vp   = (u16*)(ws + OFF_VP);
    u16*   xu   = (u16*)(ws + OFF_XU);

    hipMemsetAsync(bar, 0, 256, stream);
    prep_probe<<<dim3(1), dim3(64), 0, stream>>>(x, flag);
    prep_misc<<<dim3(144), dim3(256), 0, stream>>>(bb0, bb1, bb2, bb3, bias, h0, hbf, flag);
    prep_ut<<<dim3(2048), dim3(256), 0, stream>>>(U0, U1, U2, U3, Ut, flag);
    prep_vp<<<dim3(2048), dim3(256), 0, stream>>>(V0, V1, V2, V3, Vp, flag);
    gemm_xu<<<dim3(4096), dim3(256), 0, stream>>>(x, Ut, bias, xu, flag);
    lstm_rec<<<dim3(NBLK), dim3(256), 0, stream>>>(xu, Vp, c0, hbf, (void*)d_out, bar, flag);
}